// Round 4
// baseline (60.835 us; speedup 1.0000x reference)
//
#include <hip/hip_runtime.h>

#define NCOL 90                       // 5*B + C = 10 + 80
#define CB 32                         // cells per chunk
#define CHUNKF (CB * NCOL)            // 2880 floats per array per chunk (11520 B)
#define NBLOCKS 768                   // 3 blocks/CU exactly -> all resident
#define LAMBDA_COORD 5.0f
#define LAMBDA_NOOBJ 0.5f

typedef const __attribute__((address_space(1))) void* gas_ptr;
typedef __attribute__((address_space(3))) void* las_ptr;

__device__ __forceinline__ void dma16(const float* g, float* l) {
    __builtin_amdgcn_global_load_lds((gas_ptr)g, (las_ptr)l, 16, 0, 0);
}
__device__ __forceinline__ void dma4(const float* g, float* l) {
    __builtin_amdgcn_global_load_lds((gas_ptr)g, (las_ptr)l, 4, 0, 0);
}

// 24 DMA ops per chunk (pred: 11x dma16 + 1x dma4, targ: same), round-robined
// so every wave issues exactly 6 (vmcnt counting relies on this).
__device__ __forceinline__ void issue_chunk(const float* pred, const float* targ,
                                            float* buf, int c, int wave, int lane) {
    const float* psrc = pred + (size_t)c * CHUNKF;
    const float* tsrc = targ + (size_t)c * CHUNKF;
#pragma unroll
    for (int m = 0; m < 6; ++m) {
        int o = wave + 4 * m;                 // 0..23
        int a = (o >= 12) ? 1 : 0;            // 0=pred, 1=targ
        int j = o - a * 12;                   // 0..11
        const float* s = a ? tsrc : psrc;
        float* d = buf + (a ? CHUNKF : 0);
        if (j < 11) dma16(s + j * 256 + lane * 4, d + j * 256);
        else        dma4 (s + 2816 + lane,        d + 2816);
    }
}

// Per-chunk loss from LDS buffer: [0,2880)=pred cells, [2880,5760)=targ cells.
// 8 lanes per cell; lane r sweeps class float2s at cols 2r+16k; box on r==0.
__device__ __forceinline__ float chunk_loss(const float* buf, int tid) {
    const float inv_s = 1.0f / 7.0f;
    const int g = tid >> 3;                   // cell 0..31
    const int r = tid & 7;
    const float* lp = buf + g * NCOL;
    const float* lt = buf + CHUNKF + g * NCOL;

    float cls_acc = 0.0f;
#pragma unroll
    for (int k = 0; k < 6; ++k) {
        int col = 2 * r + 16 * k;
        if (col >= 10 && col < NCOL) {        // pairs never straddle boundary
            float2 a = *reinterpret_cast<const float2*>(lp + col);
            float2 b = *reinterpret_cast<const float2*>(lt + col);
            float dx = a.x - b.x;
            float dy = a.y - b.y;
            cls_acc += dx * dx + dy * dy;
        }
    }

    float conf_t  = lt[4];
    float coord_m = (conf_t > 0.0f) ? 1.0f : 0.0f;
    float res = coord_m * cls_acc;

    if (r == 0) {
        float p[10], t[10];
#pragma unroll
        for (int i = 0; i < 10; ++i) { p[i] = lp[i]; t[i] = lt[i]; }

        float noobj_m = (conf_t == 0.0f) ? 1.0f : 0.0f;
        float d4 = p[4] - t[4];
        float d9 = p[9] - t[9];
        float noobj = noobj_m * (d4 * d4 + d9 * d9);

        float tax = t[0] * inv_s - 0.5f * t[2];
        float tay = t[1] * inv_s - 0.5f * t[3];
        float tbx = tax * inv_s + 0.5f * t[2];
        float tby = tay * inv_s + 0.5f * t[3];
        float t_area = (tbx - tax) * (tby - tay);

        float pax[2], pay[2], pbx[2], pby[2], iou[2];
#pragma unroll
        for (int b = 0; b < 2; ++b) {
            const float* q = p + 5 * b;
            float ax = q[0] * inv_s - 0.5f * q[2];
            float ay = q[1] * inv_s - 0.5f * q[3];
            float bx = ax * inv_s + 0.5f * q[2];
            float by = ay * inv_s + 0.5f * q[3];
            pax[b] = ax; pay[b] = ay; pbx[b] = bx; pby[b] = by;
            float tlx = fmaxf(ax, tax);
            float tly = fmaxf(ay, tay);
            float brx = fminf(bx, tbx);
            float bry = fminf(by, tby);
            float w = fmaxf(brx - tlx, 0.0f);
            float h = fmaxf(bry - tly, 0.0f);
            float inter = w * h;
            float parea = (bx - ax) * (by - ay);
            iou[b] = inter / (parea + t_area - inter);
        }

        int idx = (iou[1] > iou[0]) ? 1 : 0;  // argmax, first-max-on-tie
        float tiou = idx ? iou[1] : iou[0];

        float psx = idx ? pax[1] : pax[0];
        float psy = idx ? pay[1] : pay[0];
        float psw = idx ? pbx[1] : pbx[0];
        float psh = idx ? pby[1] : pby[0];
        float psc = idx ? p[9] : p[4];

        float tsx, tsy, tsw, tsh;
        if (idx == 0) { tsx = tax; tsy = tay; tsw = tbx; tsh = tby; }
        else          { tsx = t[5]; tsy = t[6]; tsw = t[7]; tsh = t[8]; }

        float dx = psx - tsx;
        float dy = psy - tsy;
        float dw = psw - tsw;
        float dh = psh - tsh;
        float xy = dx * dx + dy * dy;
        float wh = dw * dw + dh * dh;
        float dc = psc - tiou;

        res += coord_m * (LAMBDA_COORD * (xy + wh) + dc * dc)
             + LAMBDA_NOOBJ * noobj;
    }
    return res;
}

__global__ __launch_bounds__(256) void yolo_kernel(
    const float* __restrict__ pred,
    const float* __restrict__ targ,
    float* __restrict__ partials,
    unsigned int* __restrict__ counter,
    float* __restrict__ out,
    int nchunks)
{
    __shared__ float lds[2][2 * CHUNKF];      // 46080 B
    __shared__ float red[4];
    __shared__ int is_last;

    const int wave = threadIdx.x >> 6;
    const int lane = threadIdx.x & 63;

    float acc = 0.0f;
    int cur = 0;
    int c = blockIdx.x;
    issue_chunk(pred, targ, lds[0], c, wave, lane);

    while (true) {
        int cn = c + NBLOCKS;
        bool hn = (cn < nchunks);             // block-uniform
        if (hn) {
            issue_chunk(pred, targ, lds[cur ^ 1], cn, wave, lane);
            asm volatile("s_waitcnt vmcnt(6)" ::: "memory");  // prev chunk done
        } else {
            asm volatile("s_waitcnt vmcnt(0)" ::: "memory");
        }
        __builtin_amdgcn_s_barrier();         // all waves' DMAs for cur landed
        acc += chunk_loss(lds[cur], threadIdx.x);
        __builtin_amdgcn_s_barrier();         // all done reading cur before reuse
        if (!hn) break;
        c = cn; cur ^= 1;
    }

    // block reduce
#pragma unroll
    for (int off = 32; off > 0; off >>= 1)
        acc += __shfl_down(acc, off, 64);
    if (lane == 0) red[wave] = acc;
    __syncthreads();

    if (threadIdx.x == 0) {
        float val = red[0] + red[1] + red[2] + red[3];
        __hip_atomic_store(&partials[blockIdx.x], val,
                           __ATOMIC_RELAXED, __HIP_MEMORY_SCOPE_AGENT);
        __threadfence();                      // release partials before count
        unsigned int prev = __hip_atomic_fetch_add(counter, 1u,
                           __ATOMIC_ACQ_REL, __HIP_MEMORY_SCOPE_AGENT);
        is_last = (prev == NBLOCKS - 1) ? 1 : 0;
    }
    __syncthreads();

    if (is_last) {                            // last block: final sum
        float s = 0.0f;
        for (int i = threadIdx.x; i < NBLOCKS; i += 256)
            s += __hip_atomic_load(&partials[i],
                                   __ATOMIC_RELAXED, __HIP_MEMORY_SCOPE_AGENT);
#pragma unroll
        for (int off = 32; off > 0; off >>= 1)
            s += __shfl_down(s, off, 64);
        if (lane == 0) red[wave] = s;
        __syncthreads();
        if (threadIdx.x == 0)
            out[0] = (red[0] + red[1] + red[2] + red[3]) * (1.0f / 4096.0f);
    }
}

extern "C" void kernel_launch(void* const* d_in, const int* in_sizes, int n_in,
                              void* d_out, int out_size, void* d_ws, size_t ws_size,
                              hipStream_t stream) {
    const float* pred = (const float*)d_in[0];
    const float* targ = (const float*)d_in[1];
    float* out = (float*)d_out;

    int ncells  = in_sizes[0] / NCOL;         // 200704
    int nchunks = ncells / CB;                // 6272 (exact)

    float* partials        = (float*)d_ws;                    // 768 floats
    unsigned int* counter  = (unsigned int*)((char*)d_ws + 4096);

    hipMemsetAsync(counter, 0, sizeof(unsigned int), stream); // graph-safe
    yolo_kernel<<<NBLOCKS, 256, 0, stream>>>(pred, targ, partials, counter,
                                             out, nchunks);
}